// Round 7
// baseline (1934.638 us; speedup 1.0000x reference)
//
#include <hip/hip_runtime.h>
#include <cstdint>
#include <cstddef>

typedef __bf16 bf16;
typedef __bf16 bf16x8 __attribute__((ext_vector_type(8)));
typedef __bf16 bf16x4 __attribute__((ext_vector_type(4)));
typedef float f32x4 __attribute__((ext_vector_type(4)));
typedef long long i64;

#define S_DIM 4096
#define N_DIM 16384
#define D_DIM 768
#define NZ 8
#define KSLICE (N_DIM / NZ)   // 2048

static constexpr float SCALE = 0.03608439182435161f; // 768^-0.5

// ---------------------------------------------------------------- async 16B global->LDS
__device__ inline void gl_lds16(const void* g, void* l) {
  __builtin_amdgcn_global_load_lds((const __attribute__((address_space(1))) void*)g,
                                   (__attribute__((address_space(3))) void*)l, 16, 0, 0);
}

__device__ inline unsigned char to_fp8(float x) {
  int p = __builtin_amdgcn_cvt_pk_fp8_f32(x, x, 0, false);
  return (unsigned char)(p & 0xff);
}

// ---------------------------------------------------------------- bf16 GEMM core  C = A @ B^T
// A: bf16 [M,K] rm (stride lda). B: bf16 [N,K] rm (stride ldb).
// LDS tile rows 64 B; 16B-chunk swizzle c' = c ^ (r&3) ^ ((r>>2)&3).
// EPIL: 0 = +bias(col) -> bf16
//       4 = relu(x+bias) -> bf16
//       5 = x + bias + res -> f32
//       9 = +bias(row) -> fp8
struct GemmArgs {
  const bf16* A; const bf16* B;
  const float* bias;
  float* outF; bf16* outB; unsigned char* outP8;
  const float* res;
  float* lsum;
  int M, N, K, lda, ldb;
  float scale;
};

template<int EPIL>
__device__ __forceinline__ void gemm_core(const GemmArgs& g, const int bm, const int bn,
                                          bf16* sA, bf16* sB) {
  const int tid  = threadIdx.x;
  const int wave = tid >> 6;
  const int lane = tid & 63;
  const int quad = lane >> 4;
  const int l15  = lane & 15;
  const int wm = (wave >> 1) * 64;
  const int wn = (wave & 1) * 64;

  f32x4 acc[4][4];
#pragma unroll
  for (int t = 0; t < 4; ++t)
#pragma unroll
    for (int u = 0; u < 4; ++u) acc[t][u] = (f32x4){0.f, 0.f, 0.f, 0.f};

  // staging: seg s in [0,512); r = s>>2, chunk c = s&3 (16B); swizzled source
  const int s0 = wave * 64 + lane;
  const int s1 = 256 + s0;
  const int r0 = s0 >> 2, c0 = s0 & 3, x0 = (r0 & 3) ^ ((r0 >> 2) & 3);
  const int r1 = s1 >> 2, c1 = s1 & 3, x1 = (r1 & 3) ^ ((r1 >> 2) & 3);
  const size_t lda = (size_t)g.lda, ldb = (size_t)g.ldb;
  const bf16* gA0 = g.A + (size_t)(bm + r0) * lda + (c0 ^ x0) * 8;
  const bf16* gA1 = g.A + (size_t)(bm + r1) * lda + (c1 ^ x1) * 8;
  const bf16* gB0 = g.B + (size_t)(bn + r0) * ldb + (c0 ^ x0) * 8;
  const bf16* gB1 = g.B + (size_t)(bn + r1) * ldb + (c1 ^ x1) * 8;
  bf16* lA0 = sA + s0 * 8;  bf16* lA1 = sA + s1 * 8;
  bf16* lB0 = sB + s0 * 8;  bf16* lB1 = sB + s1 * 8;

  const int xr = (l15 & 3) ^ ((l15 >> 2) & 3);   // frag-read swizzle (row ≡ l15 mod 16)
  const int qx = (quad ^ xr) * 8;

  for (int k0 = 0; k0 < g.K; k0 += 32) {
    __syncthreads();
    gl_lds16(gA0 + k0, lA0);
    gl_lds16(gA1 + k0, lA1);
    gl_lds16(gB0 + k0, lB0);
    gl_lds16(gB1 + k0, lB1);
    __syncthreads();
    bf16x8 af[4], bv[4];
#pragma unroll
    for (int t = 0; t < 4; ++t)
      af[t] = *(const bf16x8*)(sA + (wm + t * 16 + l15) * 32 + qx);
#pragma unroll
    for (int u = 0; u < 4; ++u)
      bv[u] = *(const bf16x8*)(sB + (wn + u * 16 + l15) * 32 + qx);
#pragma unroll
    for (int t = 0; t < 4; ++t)
#pragma unroll
      for (int u = 0; u < 4; ++u)
        acc[t][u] = __builtin_amdgcn_mfma_f32_16x16x32_bf16(af[t], bv[u], acc[t][u], 0, 0, 0);
  }

  const int ldc = g.N;
#pragma unroll
  for (int t = 0; t < 4; ++t) {
    const int rbase = bm + wm + t * 16 + quad * 4;
#pragma unroll
    for (int u = 0; u < 4; ++u) {
      const int col = bn + wn + u * 16 + l15;
      const float cbias = (EPIL == 0 || EPIL == 4 || EPIL == 5) ? g.bias[col] : 0.f;
#pragma unroll
      for (int r = 0; r < 4; ++r) {
        const size_t idx = (size_t)(rbase + r) * ldc + col;
        const float v = acc[t][u][r];
        if (EPIL == 0) g.outB[idx] = (bf16)(v + cbias);
        else if (EPIL == 4) { float x = v + cbias; g.outB[idx] = (bf16)(x > 0.f ? x : 0.f); }
        else if (EPIL == 5) g.outF[idx] = v + cbias + g.res[idx];
        else if (EPIL == 9) g.outP8[idx] = to_fp8(v + g.bias[rbase + r]);
      }
    }
  }
}

#define GEMM_SHARED __shared__ __align__(16) bf16 sA[128 * 32]; __shared__ __align__(16) bf16 sB[128 * 32]

__global__ __launch_bounds__(256) void k_qgemm(GemmArgs g) {
  GEMM_SHARED; gemm_core<0>(g, blockIdx.y * 128, blockIdx.x * 128, sA, sB);
}
__global__ __launch_bounds__(256) void k_kgemm(GemmArgs g) {
  GEMM_SHARED; gemm_core<0>(g, blockIdx.y * 128, blockIdx.x * 128, sA, sB);
}
__global__ __launch_bounds__(256) void k_vtgemm(GemmArgs g) {
  GEMM_SHARED; gemm_core<9>(g, blockIdx.y * 128, blockIdx.x * 128, sA, sB);
}
__global__ __launch_bounds__(256) void k_relu(GemmArgs g) {
  GEMM_SHARED; gemm_core<4>(g, blockIdx.y * 128, blockIdx.x * 128, sA, sB);
}
__global__ __launch_bounds__(256) void k_resid(GemmArgs g) {
  GEMM_SHARED; gemm_core<5>(g, blockIdx.y * 128, blockIdx.x * 128, sA, sB);
}
__global__ __launch_bounds__(256) void k_dual(GemmArgs a, GemmArgs b, int split) {
  GEMM_SHARED;
  if ((int)blockIdx.x < split) gemm_core<0>(a, blockIdx.y * 128, blockIdx.x * 128, sA, sB);
  else                         gemm_core<0>(b, blockIdx.y * 128, (blockIdx.x - split) * 128, sA, sB);
}

// ---------------------------------------------------------------- dots GEMM (512 thr, 128x256)
// C = q @ k^T over K=768; epilogue exp(scale*x) -> fp8 P~, rowsum atomics into lsum.
// 8 waves, each 64x64. A: bf16 [S,768], B: bf16 [N,768].
__global__ __launch_bounds__(512) void k_dots(GemmArgs g) {
  __shared__ __align__(16) bf16 sA[128 * 32];   // 8 KB
  __shared__ __align__(16) bf16 sB[256 * 32];   // 16 KB
  const int tid  = threadIdx.x;
  const int wave = tid >> 6;
  const int lane = tid & 63;
  const int quad = lane >> 4;
  const int l15  = lane & 15;
  const int bm = blockIdx.y * 128;
  const int bn = blockIdx.x * 256;
  const int wm = (wave >> 2) * 64;
  const int wn = (wave & 3) * 64;

  f32x4 acc[4][4];
#pragma unroll
  for (int t = 0; t < 4; ++t)
#pragma unroll
    for (int u = 0; u < 4; ++u) acc[t][u] = (f32x4){0.f, 0.f, 0.f, 0.f};

  // staging: A 512 segs (1/thread), B 1024 segs (2/thread); seg s: r=s>>2, c=s&3
  const size_t lda = (size_t)g.lda, ldb = (size_t)g.ldb;
  const int sa = tid,        raA = sa >> 2, caA = sa & 3, xaA = (raA & 3) ^ ((raA >> 2) & 3);
  const int sb0 = tid,       rb0 = sb0 >> 2, cb0 = sb0 & 3, xb0 = (rb0 & 3) ^ ((rb0 >> 2) & 3);
  const int sb1 = tid + 512, rb1 = sb1 >> 2, cb1 = sb1 & 3, xb1 = (rb1 & 3) ^ ((rb1 >> 2) & 3);
  const bf16* gA  = g.A + (size_t)(bm + raA) * lda + (caA ^ xaA) * 8;
  const bf16* gB0 = g.B + (size_t)(bn + rb0) * ldb + (cb0 ^ xb0) * 8;
  const bf16* gB1 = g.B + (size_t)(bn + rb1) * ldb + (cb1 ^ xb1) * 8;
  bf16* lA  = sA + sa * 8;
  bf16* lB0 = sB + sb0 * 8;
  bf16* lB1 = sB + sb1 * 8;

  const int xr = (l15 & 3) ^ ((l15 >> 2) & 3);
  const int qx = (quad ^ xr) * 8;

  for (int k0 = 0; k0 < D_DIM; k0 += 32) {
    __syncthreads();
    gl_lds16(gA + k0, lA);
    gl_lds16(gB0 + k0, lB0);
    gl_lds16(gB1 + k0, lB1);
    __syncthreads();
    bf16x8 af[4], bv[4];
#pragma unroll
    for (int t = 0; t < 4; ++t)
      af[t] = *(const bf16x8*)(sA + (wm + t * 16 + l15) * 32 + qx);
#pragma unroll
    for (int u = 0; u < 4; ++u)
      bv[u] = *(const bf16x8*)(sB + (wn + u * 16 + l15) * 32 + qx);
#pragma unroll
    for (int t = 0; t < 4; ++t)
#pragma unroll
      for (int u = 0; u < 4; ++u)
        acc[t][u] = __builtin_amdgcn_mfma_f32_16x16x32_bf16(af[t], bv[u], acc[t][u], 0, 0, 0);
  }

  const int ldc = g.N;
#pragma unroll
  for (int t = 0; t < 4; ++t) {
    const int rbase = bm + wm + t * 16 + quad * 4;
    float rsum[4] = {0.f, 0.f, 0.f, 0.f};
#pragma unroll
    for (int u = 0; u < 4; ++u) {
      const int col = bn + wn + u * 16 + l15;
#pragma unroll
      for (int r = 0; r < 4; ++r) {
        float e = __expf(acc[t][u][r] * g.scale);
        g.outP8[(size_t)(rbase + r) * ldc + col] = to_fp8(e);
        rsum[r] += e;
      }
    }
#pragma unroll
    for (int m = 1; m < 16; m <<= 1)
#pragma unroll
      for (int r = 0; r < 4; ++r) rsum[r] += __shfl_xor(rsum[r], m, 64);
    if (l15 == 0)
#pragma unroll
      for (int r = 0; r < 4; ++r) atomicAdd(&g.lsum[rbase + r], rsum[r]);
  }
}

// ---------------------------------------------------------------- fp8 updates GEMM
// C[128x256] per block, 8 waves (512 thr), each wave 64x64. Single pass (INIT store).
// A: fp8 [4096, N] (P~), B: fp8 [768, N] (v^T). z-slice of K -> private bf16 partial.
struct F8Args {
  const unsigned char* A; const unsigned char* B;
  bf16* out;       // NZ partial buffers, each S_DIM*D_DIM, contiguous
  int lda, ldb;
};

__global__ __launch_bounds__(512) void k_upd(F8Args u) {
  __shared__ __align__(16) unsigned char sA[128 * 32];
  __shared__ __align__(16) unsigned char sB[256 * 32];
  const int tid  = threadIdx.x;
  const int wave = tid >> 6;
  const int lane = tid & 63;
  const int quad = lane >> 4;
  const int l15  = lane & 15;
  const int bm = blockIdx.y * 128;
  const int bn = blockIdx.x * 256;
  const int z  = blockIdx.z;
  const int wm = (wave >> 2) * 64;
  const int wn = (wave & 3) * 64;

  const unsigned char* A = u.A + (size_t)z * KSLICE;
  const unsigned char* B = u.B + (size_t)z * KSLICE;
  bf16* out = u.out + (size_t)z * S_DIM * D_DIM;

  f32x4 acc[4][4];
#pragma unroll
  for (int t = 0; t < 4; ++t)
#pragma unroll
    for (int u2 = 0; u2 < 4; ++u2) acc[t][u2] = (f32x4){0.f, 0.f, 0.f, 0.f};

  // staging per K-step: B = 512 segs of 16B (all threads), A = 256 segs (threads<256)
  const size_t lda = (size_t)u.lda, ldb = (size_t)u.ldb;
  const int rb = tid >> 1, hb = tid & 1;
  const unsigned char* gB = B + (size_t)(bn + rb) * ldb + ((hb ^ ((rb >> 2) & 1)) * 16);
  unsigned char* lB = sB + tid * 16;
  const int ta = tid & 255;
  const int ra = ta >> 1, ha = ta & 1;
  const unsigned char* gA = A + (size_t)(bm + ra) * lda + ((ha ^ ((ra >> 2) & 1)) * 16);
  unsigned char* lA = sA + ta * 16;
  const bool doA = (tid < 256);

  const int xh = (l15 >> 2) & 1;
  const int qoff = (((quad >> 1) ^ xh) * 16) + (quad & 1) * 8;

  for (int k0 = 0; k0 < KSLICE; k0 += 32) {
    __syncthreads();
    if (doA) gl_lds16(gA + k0, lA);
    gl_lds16(gB + k0, lB);
    __syncthreads();
    i64 af[4], bv[4];
#pragma unroll
    for (int t = 0; t < 4; ++t)
      af[t] = *(const i64*)(sA + (wm + t * 16 + l15) * 32 + qoff);
#pragma unroll
    for (int u2 = 0; u2 < 4; ++u2)
      bv[u2] = *(const i64*)(sB + (wn + u2 * 16 + l15) * 32 + qoff);
#pragma unroll
    for (int t = 0; t < 4; ++t)
#pragma unroll
      for (int u2 = 0; u2 < 4; ++u2)
        acc[t][u2] = __builtin_amdgcn_mfma_f32_16x16x32_fp8_fp8(af[t], bv[u2], acc[t][u2], 0, 0, 0);
  }

#pragma unroll
  for (int t = 0; t < 4; ++t) {
    const int rbase = bm + wm + t * 16 + quad * 4;
#pragma unroll
    for (int u2 = 0; u2 < 4; ++u2) {
      const int col = bn + wn + u2 * 16 + l15;
#pragma unroll
      for (int r = 0; r < 4; ++r)
        out[(size_t)(rbase + r) * D_DIM + col] = (bf16)acc[t][u2][r];
    }
  }
}

// ---------------------------------------------------------------- reduce NZ bf16 partials + /lsum
__global__ void reduce_div_k(const bf16* __restrict__ bufs, const float* __restrict__ lsum,
                             bf16* __restrict__ out) {
  const int idx = blockIdx.x * 256 + threadIdx.x;   // over S*192 bf16x4 groups
  const int row = idx / 192;
  const float inv = 1.0f / lsum[row];
  float s0 = 0.f, s1 = 0.f, s2 = 0.f, s3 = 0.f;
#pragma unroll
  for (int z = 0; z < NZ; ++z) {
    bf16x4 v = ((const bf16x4*)(bufs + (size_t)z * S_DIM * D_DIM))[idx];
    s0 += (float)v[0]; s1 += (float)v[1]; s2 += (float)v[2]; s3 += (float)v[3];
  }
  bf16x4 y;
  y[0] = (bf16)(s0 * inv); y[1] = (bf16)(s1 * inv);
  y[2] = (bf16)(s2 * inv); y[3] = (bf16)(s3 * inv);
  ((bf16x4*)out)[idx] = y;
}

// ---------------------------------------------------------------- LayerNorm row stats (wave/row)
__global__ void ln_stats_k(const float* __restrict__ X, float2* __restrict__ st) {
  const int row  = blockIdx.x * 4 + (threadIdx.x >> 6);
  const int lane = threadIdx.x & 63;
  const float4* xr = (const float4*)(X + (size_t)row * 768);
  float s = 0.f, ss = 0.f;
#pragma unroll
  for (int i = 0; i < 3; ++i) {
    float4 v = xr[lane + 64 * i];
    s  += v.x + v.y + v.z + v.w;
    ss += v.x * v.x + v.y * v.y + v.z * v.z + v.w * v.w;
  }
#pragma unroll
  for (int m = 1; m < 64; m <<= 1) { s += __shfl_xor(s, m, 64); ss += __shfl_xor(ss, m, 64); }
  if (lane == 0) {
    float mean = s * (1.f / 768.f);
    float var  = ss * (1.f / 768.f) - mean * mean;
    st[row] = make_float2(mean, rsqrtf(var + 1e-5f));
  }
}

// ---------------------------------------------------------------- LN apply -> bf16
__global__ void ln_apply_k(const float* __restrict__ X, const float2* __restrict__ st,
                           const float* __restrict__ gam, const float* __restrict__ bet,
                           bf16* __restrict__ Y) {
  const int idx = blockIdx.x * 256 + threadIdx.x;
  const int row = idx / 192, c4 = idx % 192;
  const float2 s = st[row];
  float4 x  = ((const float4*)(X + (size_t)row * 768))[c4];
  float4 g4 = ((const float4*)gam)[c4];
  float4 b4 = ((const float4*)bet)[c4];
  bf16x4 y;
  y[0] = (bf16)((x.x - s.x) * s.y * g4.x + b4.x);
  y[1] = (bf16)((x.y - s.x) * s.y * g4.y + b4.y);
  y[2] = (bf16)((x.z - s.x) * s.y * g4.z + b4.z);
  y[3] = (bf16)((x.w - s.x) * s.y * g4.w + b4.w);
  ((bf16x4*)(Y + (size_t)row * 768))[c4] = y;
}

// ---------------------------------------------------------------- f32 -> bf16
__global__ void cvt_k(const float* __restrict__ X, bf16* __restrict__ Y) {
  const int i = blockIdx.x * 256 + threadIdx.x;
  float4 v = ((const float4*)X)[i];
  bf16x4 y;
  y[0] = (bf16)v.x; y[1] = (bf16)v.y; y[2] = (bf16)v.z; y[3] = (bf16)v.w;
  ((bf16x4*)Y)[i] = y;
}

// ---------------------------------------------------------------- GRU gate (bf16 gx/gh)
__device__ inline float gru1(float xr, float xz, float xn, float hr, float hz, float hn, float sp) {
  float r = 1.f / (1.f + __expf(-(xr + hr)));
  float z = 1.f / (1.f + __expf(-(xz + hz)));
  float n = tanhf(xn + r * hn);
  return (1.f - z) * n + z * sp;
}

__global__ void gru_gate_k(const bf16* __restrict__ gx, const bf16* __restrict__ gh,
                           const float* __restrict__ slots, float* __restrict__ h) {
  const int idx = blockIdx.x * 256 + threadIdx.x;
  const int row = idx / 192, c4 = idx % 192;
  const bf16x4* gxr = (const bf16x4*)(gx + (size_t)row * 2304);
  const bf16x4* ghr = (const bf16x4*)(gh + (size_t)row * 2304);
  bf16x4 xr = gxr[c4], xz = gxr[192 + c4], xn = gxr[384 + c4];
  bf16x4 hr = ghr[c4], hz = ghr[192 + c4], hn = ghr[384 + c4];
  float4 sp = ((const float4*)(slots + (size_t)row * 768))[c4];
  float4 o;
  o.x = gru1((float)xr[0], (float)xz[0], (float)xn[0], (float)hr[0], (float)hz[0], (float)hn[0], sp.x);
  o.y = gru1((float)xr[1], (float)xz[1], (float)xn[1], (float)hr[1], (float)hz[1], (float)hn[1], sp.y);
  o.z = gru1((float)xr[2], (float)xz[2], (float)xn[2], (float)hr[2], (float)hz[2], (float)hn[2], sp.z);
  o.w = gru1((float)xr[3], (float)xz[3], (float)xn[3], (float)hr[3], (float)hz[3], (float)hn[3], sp.w);
  ((float4*)(h + (size_t)row * 768))[c4] = o;
}

// ---------------------------------------------------------------- host
extern "C" void kernel_launch(void* const* d_in, const int* in_sizes, int n_in,
                              void* d_out, int out_size, void* d_ws, size_t ws_size,
                              hipStream_t stream) {
  (void)in_sizes; (void)n_in; (void)out_size; (void)ws_size;
  const float* cand  = (const float*)d_in[0];
  const float* pano  = (const float*)d_in[1];
  const float* Wq  = (const float*)d_in[2];  const float* bq  = (const float*)d_in[3];
  const float* Wk  = (const float*)d_in[4];  const float* bk  = (const float*)d_in[5];
  const float* Wv  = (const float*)d_in[6];  const float* bv  = (const float*)d_in[7];
  const float* Wih = (const float*)d_in[8];  const float* bih = (const float*)d_in[9];
  const float* Whh = (const float*)d_in[10]; const float* bhh = (const float*)d_in[11];
  const float* W1  = (const float*)d_in[12]; const float* b1  = (const float*)d_in[13];
  const float* W2  = (const float*)d_in[14]; const float* b2  = (const float*)d_in[15];
  const float* g_in = (const float*)d_in[16]; const float* be_in = (const float*)d_in[17];
  const float* g_sl = (const float*)d_in[18]; const float* be_sl = (const float*)d_in[19];
  const float* g_ff = (const float*)d_in[20]; const float* be_ff = (const float*)d_in[21];

  const size_t WU = (size_t)D_DIM * D_DIM;

  char* base = (char*)d_ws;
  size_t off = 0;
  auto alloc = [&](size_t bytes) -> void* {
    void* r = base + off;
    off = (off + bytes + 255) & ~(size_t)255;
    return r;
  };

  bf16* wq_bf  = (bf16*)alloc(WU * 2);
  bf16* wk_bf  = (bf16*)alloc(WU * 2);
  bf16* wv_bf  = (bf16*)alloc(WU * 2);
  bf16* wih_bf = (bf16*)alloc(3 * WU * 2);
  bf16* whh_bf = (bf16*)alloc(3 * WU * 2);
  bf16* w1_bf  = (bf16*)alloc(WU * 2);
  bf16* w2_bf  = (bf16*)alloc(WU * 2);
  bf16* k_bf   = (bf16*)alloc((size_t)N_DIM * D_DIM * 2);
  unsigned char* vt_f8 = (unsigned char*)alloc((size_t)N_DIM * D_DIM);  // [768,16384] fp8
  float* slots = (float*)alloc((size_t)S_DIM * D_DIM * 4);
  bf16* slots_bf = (bf16*)alloc((size_t)S_DIM * D_DIM * 2);
  float2* statsP = (float2*)alloc((size_t)N_DIM * 8);
  float2* statsS = (float2*)alloc((size_t)S_DIM * 8);
  bf16* slotsln = (bf16*)alloc((size_t)S_DIM * D_DIM * 2);   // also hln (disjoint lifetime)
  bf16* q_bf    = (bf16*)alloc((size_t)S_DIM * D_DIM * 2);   // also m1 (disjoint lifetime)
  bf16* upd_bf  = (bf16*)alloc((size_t)S_DIM * D_DIM * 2);
  float* lsum   = (float*)alloc((size_t)S_DIM * 4);
  bf16* hln_bf = slotsln;
  bf16* m1_bf  = q_bf;
  // arena 112 MiB:
  //  attn phase: [0,64) P~ fp8 (S x N) | [64,112) partials (NZ=8 x 6 MiB bf16)
  //  gru  phase: [0,18) gx | [18,36) gh | [36,48) hbuf (f32)
  //  setup     : [0,24) panoln
  const size_t PCH = (size_t)S_DIM * N_DIM;             // 64 MiB fp8
  const size_t PBF = (size_t)NZ * S_DIM * D_DIM * 2;    // 48 MiB
  char* arena = (char*)alloc(PCH + PBF);
  bf16* panoln = (bf16*)arena;
  unsigned char* Pfull = (unsigned char*)arena;
  bf16* pbufs = (bf16*)(arena + PCH);
  bf16* gx = (bf16*)arena;
  bf16* gh = (bf16*)(arena + (size_t)S_DIM * 3 * D_DIM * 2);
  float* hbuf = (float*)(arena + 2 * (size_t)S_DIM * 3 * D_DIM * 2);

  // ---- weights to bf16
  cvt_k<<<dim3(WU / 1024), 256, 0, stream>>>(Wq, wq_bf);
  cvt_k<<<dim3(WU / 1024), 256, 0, stream>>>(Wk, wk_bf);
  cvt_k<<<dim3(WU / 1024), 256, 0, stream>>>(Wv, wv_bf);
  cvt_k<<<dim3(3 * WU / 1024), 256, 0, stream>>>(Wih, wih_bf);
  cvt_k<<<dim3(3 * WU / 1024), 256, 0, stream>>>(Whh, whh_bf);
  cvt_k<<<dim3(WU / 1024), 256, 0, stream>>>(W1, w1_bf);
  cvt_k<<<dim3(WU / 1024), 256, 0, stream>>>(W2, w2_bf);

  // ---- pano LN, k (bf16), v^T (fp8)
  ln_stats_k<<<dim3(N_DIM / 4), 256, 0, stream>>>(pano, statsP);
  ln_apply_k<<<dim3(N_DIM * 192 / 256), 256, 0, stream>>>(pano, statsP, g_in, be_in, panoln);
  {
    GemmArgs ak{};
    ak.A = panoln; ak.B = wk_bf; ak.bias = bk; ak.outB = k_bf;
    ak.M = N_DIM; ak.N = D_DIM; ak.K = D_DIM; ak.lda = D_DIM; ak.ldb = D_DIM;
    k_kgemm<<<dim3(6, 128), 256, 0, stream>>>(ak);
    GemmArgs av{};  // v^T = Wv @ panoln^T -> fp8 [768, 16384]
    av.A = wv_bf; av.B = panoln; av.bias = bv; av.outP8 = vt_f8;
    av.M = D_DIM; av.N = N_DIM; av.K = D_DIM; av.lda = D_DIM; av.ldb = D_DIM;
    k_vtgemm<<<dim3(128, 6), 256, 0, stream>>>(av);
  }

  // ---- slots init
  hipMemcpyAsync(slots, cand, (size_t)S_DIM * D_DIM * 4, hipMemcpyDeviceToDevice, stream);
  cvt_k<<<dim3(S_DIM * D_DIM / 1024), 256, 0, stream>>>(cand, slots_bf);

  for (int iter = 0; iter < 3; ++iter) {
    // q = LN(slots) @ Wq^T + bq
    ln_stats_k<<<dim3(S_DIM / 4), 256, 0, stream>>>(slots, statsS);
    ln_apply_k<<<dim3(S_DIM * 192 / 256), 256, 0, stream>>>(slots, statsS, g_sl, be_sl, slotsln);
    GemmArgs aq{};
    aq.A = slotsln; aq.B = wq_bf; aq.bias = bq; aq.outB = q_bf;
    aq.M = S_DIM; aq.N = D_DIM; aq.K = D_DIM; aq.lda = D_DIM; aq.ldb = D_DIM;
    k_qgemm<<<dim3(6, 32), 256, 0, stream>>>(aq);

    // attention, single pass over full N
    hipMemsetAsync(lsum, 0, (size_t)S_DIM * 4, stream);
    {
      GemmArgs ad{};
      ad.A = q_bf; ad.B = k_bf;
      ad.outP8 = Pfull; ad.lsum = lsum; ad.scale = SCALE;
      ad.M = S_DIM; ad.N = N_DIM; ad.K = D_DIM; ad.lda = D_DIM; ad.ldb = D_DIM;
      k_dots<<<dim3(N_DIM / 256, S_DIM / 128), 512, 0, stream>>>(ad);

      F8Args au{};
      au.A = Pfull; au.B = vt_f8;
      au.out = pbufs; au.lda = N_DIM; au.ldb = N_DIM;
      k_upd<<<dim3(3, 32, NZ), 512, 0, stream>>>(au);
    }
    reduce_div_k<<<dim3(S_DIM * 192 / 256), 256, 0, stream>>>(pbufs, lsum, upd_bf);

    // GRU: gx = upd @ Wih^T + bih ; gh = slots @ Whh^T + bhh
    {
      GemmArgs agx{};
      agx.A = upd_bf; agx.B = wih_bf; agx.bias = bih; agx.outB = gx;
      agx.M = S_DIM; agx.N = 3 * D_DIM; agx.K = D_DIM; agx.lda = D_DIM; agx.ldb = D_DIM;
      GemmArgs agh{};
      agh.A = slots_bf; agh.B = whh_bf; agh.bias = bhh; agh.outB = gh;
      agh.M = S_DIM; agh.N = 3 * D_DIM; agh.K = D_DIM; agh.lda = D_DIM; agh.ldb = D_DIM;
      k_dual<<<dim3(36, 32), 256, 0, stream>>>(agx, agh, 18);
    }
    gru_gate_k<<<dim3(S_DIM * 192 / 256), 256, 0, stream>>>(gx, gh, slots, hbuf);

    // MLP with residual
    ln_stats_k<<<dim3(S_DIM / 4), 256, 0, stream>>>(hbuf, statsS);
    ln_apply_k<<<dim3(S_DIM * 192 / 256), 256, 0, stream>>>(hbuf, statsS, g_ff, be_ff, hln_bf);
    GemmArgs am1{};
    am1.A = hln_bf; am1.B = w1_bf; am1.bias = b1; am1.outB = m1_bf;
    am1.M = S_DIM; am1.N = D_DIM; am1.K = D_DIM; am1.lda = D_DIM; am1.ldb = D_DIM;
    k_relu<<<dim3(6, 32), 256, 0, stream>>>(am1);
    GemmArgs am2{};
    am2.A = m1_bf; am2.B = w2_bf; am2.bias = b2; am2.res = hbuf;
    am2.outF = (iter == 2) ? (float*)d_out : slots;
    am2.M = S_DIM; am2.N = D_DIM; am2.K = D_DIM; am2.lda = D_DIM; am2.ldb = D_DIM;
    k_resid<<<dim3(6, 32), 256, 0, stream>>>(am2);

    if (iter < 2)
      cvt_k<<<dim3(S_DIM * D_DIM / 1024), 256, 0, stream>>>(slots, slots_bf);
  }
}

// Round 8
// 1735.463 us; speedup vs baseline: 1.1148x; 1.1148x over previous
//
#include <hip/hip_runtime.h>
#include <cstdint>
#include <cstddef>

typedef __bf16 bf16;
typedef __bf16 bf16x8 __attribute__((ext_vector_type(8)));
typedef __bf16 bf16x4 __attribute__((ext_vector_type(4)));
typedef float f32x4 __attribute__((ext_vector_type(4)));
typedef long long i64;

#define S_DIM 4096
#define N_DIM 16384
#define D_DIM 768
#define NZ 8
#define KSLICE (N_DIM / NZ)   // 2048

static constexpr float SCALE = 0.03608439182435161f; // 768^-0.5

// ---------------------------------------------------------------- async 16B global->LDS
__device__ inline void gl_lds16(const void* g, void* l) {
  __builtin_amdgcn_global_load_lds((const __attribute__((address_space(1))) void*)g,
                                   (__attribute__((address_space(3))) void*)l, 16, 0, 0);
}

__device__ inline unsigned char to_fp8(float x) {
  int p = __builtin_amdgcn_cvt_pk_fp8_f32(x, x, 0, false);
  return (unsigned char)(p & 0xff);
}

// ---------------------------------------------------------------- bf16 GEMM core  C = A @ B^T
// A: bf16 [M,K] rm (stride lda). B: bf16 [N,K] rm (stride ldb). BK=32.
// LDS tile rows 64 B; 16B-chunk swizzle c' = c ^ (r&3) ^ ((r>>2)&3).
// EPIL: 0 = +bias(col) -> bf16
//       4 = relu(x+bias) -> bf16
//       5 = x + bias + res -> f32
//       9 = +bias(row) -> fp8
struct GemmArgs {
  const bf16* A; const bf16* B;
  const float* bias;
  float* outF; bf16* outB; unsigned char* outP8;
  const float* res;
  float* lsum;
  int M, N, K, lda, ldb;
  float scale;
};

template<int EPIL>
__device__ __forceinline__ void gemm_core(const GemmArgs& g, const int bm, const int bn,
                                          bf16* sA, bf16* sB) {
  const int tid  = threadIdx.x;
  const int wave = tid >> 6;
  const int lane = tid & 63;
  const int quad = lane >> 4;
  const int l15  = lane & 15;
  const int wm = (wave >> 1) * 64;
  const int wn = (wave & 1) * 64;

  f32x4 acc[4][4];
#pragma unroll
  for (int t = 0; t < 4; ++t)
#pragma unroll
    for (int u = 0; u < 4; ++u) acc[t][u] = (f32x4){0.f, 0.f, 0.f, 0.f};

  // staging: seg s in [0,512); r = s>>2, chunk c = s&3 (16B); swizzled source
  const int s0 = wave * 64 + lane;
  const int s1 = 256 + s0;
  const int r0 = s0 >> 2, c0 = s0 & 3, x0 = (r0 & 3) ^ ((r0 >> 2) & 3);
  const int r1 = s1 >> 2, c1 = s1 & 3, x1 = (r1 & 3) ^ ((r1 >> 2) & 3);
  const size_t lda = (size_t)g.lda, ldb = (size_t)g.ldb;
  const bf16* gA0 = g.A + (size_t)(bm + r0) * lda + (c0 ^ x0) * 8;
  const bf16* gA1 = g.A + (size_t)(bm + r1) * lda + (c1 ^ x1) * 8;
  const bf16* gB0 = g.B + (size_t)(bn + r0) * ldb + (c0 ^ x0) * 8;
  const bf16* gB1 = g.B + (size_t)(bn + r1) * ldb + (c1 ^ x1) * 8;
  bf16* lA0 = sA + s0 * 8;  bf16* lA1 = sA + s1 * 8;
  bf16* lB0 = sB + s0 * 8;  bf16* lB1 = sB + s1 * 8;

  const int xr = (l15 & 3) ^ ((l15 >> 2) & 3);   // frag-read swizzle (row ≡ l15 mod 16)
  const int qx = (quad ^ xr) * 8;

  for (int k0 = 0; k0 < g.K; k0 += 32) {
    __syncthreads();
    gl_lds16(gA0 + k0, lA0);
    gl_lds16(gA1 + k0, lA1);
    gl_lds16(gB0 + k0, lB0);
    gl_lds16(gB1 + k0, lB1);
    __syncthreads();
    bf16x8 af[4], bv[4];
#pragma unroll
    for (int t = 0; t < 4; ++t)
      af[t] = *(const bf16x8*)(sA + (wm + t * 16 + l15) * 32 + qx);
#pragma unroll
    for (int u = 0; u < 4; ++u)
      bv[u] = *(const bf16x8*)(sB + (wn + u * 16 + l15) * 32 + qx);
#pragma unroll
    for (int t = 0; t < 4; ++t)
#pragma unroll
      for (int u = 0; u < 4; ++u)
        acc[t][u] = __builtin_amdgcn_mfma_f32_16x16x32_bf16(af[t], bv[u], acc[t][u], 0, 0, 0);
  }

  const int ldc = g.N;
#pragma unroll
  for (int t = 0; t < 4; ++t) {
    const int rbase = bm + wm + t * 16 + quad * 4;
#pragma unroll
    for (int u = 0; u < 4; ++u) {
      const int col = bn + wn + u * 16 + l15;
      const float cbias = (EPIL == 0 || EPIL == 4 || EPIL == 5) ? g.bias[col] : 0.f;
#pragma unroll
      for (int r = 0; r < 4; ++r) {
        const size_t idx = (size_t)(rbase + r) * ldc + col;
        const float v = acc[t][u][r];
        if (EPIL == 0) g.outB[idx] = (bf16)(v + cbias);
        else if (EPIL == 4) { float x = v + cbias; g.outB[idx] = (bf16)(x > 0.f ? x : 0.f); }
        else if (EPIL == 5) g.outF[idx] = v + cbias + g.res[idx];
        else if (EPIL == 9) g.outP8[idx] = to_fp8(v + g.bias[rbase + r]);
      }
    }
  }
}

#define GEMM_SHARED __shared__ __align__(16) bf16 sA[128 * 32]; __shared__ __align__(16) bf16 sB[128 * 32]

__global__ __launch_bounds__(256) void k_qgemm(GemmArgs g) {
  GEMM_SHARED; gemm_core<0>(g, blockIdx.y * 128, blockIdx.x * 128, sA, sB);
}
__global__ __launch_bounds__(256) void k_kgemm(GemmArgs g) {
  GEMM_SHARED; gemm_core<0>(g, blockIdx.y * 128, blockIdx.x * 128, sA, sB);
}
__global__ __launch_bounds__(256) void k_vtgemm(GemmArgs g) {
  GEMM_SHARED; gemm_core<9>(g, blockIdx.y * 128, blockIdx.x * 128, sA, sB);
}
__global__ __launch_bounds__(256) void k_relu(GemmArgs g) {
  GEMM_SHARED; gemm_core<4>(g, blockIdx.y * 128, blockIdx.x * 128, sA, sB);
}
__global__ __launch_bounds__(256) void k_resid(GemmArgs g) {
  GEMM_SHARED; gemm_core<5>(g, blockIdx.y * 128, blockIdx.x * 128, sA, sB);
}
__global__ __launch_bounds__(256) void k_dual(GemmArgs a, GemmArgs b, int split) {
  GEMM_SHARED;
  if ((int)blockIdx.x < split) gemm_core<0>(a, blockIdx.y * 128, blockIdx.x * 128, sA, sB);
  else                         gemm_core<0>(b, blockIdx.y * 128, (blockIdx.x - split) * 128, sA, sB);
}

// ---------------------------------------------------------------- dots GEMM (256 thr, 128x128, BK=64)
// C = q @ k^T over K=768; epilogue exp(scale*x) -> fp8 P~, rowsum atomics into lsum.
// LDS rows 128 B (8 x 16B chunks); staged LDS[r][c] = G[r][c ^ (r&7)].
// Frag chunk for (ks,quad) at row l15: (ks*4+quad) ^ (l15&7) -> 2-way bank aliasing (free).
__global__ __launch_bounds__(256) void k_dots(GemmArgs g) {
  __shared__ __align__(16) bf16 sA[128 * 64];   // 16 KB
  __shared__ __align__(16) bf16 sB[128 * 64];   // 16 KB
  const int tid  = threadIdx.x;
  const int wave = tid >> 6;
  const int lane = tid & 63;
  const int quad = lane >> 4;
  const int l15  = lane & 15;
  const int bm = blockIdx.y * 128;
  const int bn = blockIdx.x * 128;
  const int wm = (wave >> 1) * 64;
  const int wn = (wave & 1) * 64;

  f32x4 acc[4][4];
#pragma unroll
  for (int t = 0; t < 4; ++t)
#pragma unroll
    for (int u = 0; u < 4; ++u) acc[t][u] = (f32x4){0.f, 0.f, 0.f, 0.f};

  // staging: 1024 segs of 16B per buffer; thread handles segs tid + 256*j (j=0..3)
  // seg s: r = s>>3 = (tid>>3)+32j, c = tid&7 ; global chunk = c ^ (r&7) (j-invariant)
  const size_t lda = (size_t)g.lda, ldb = (size_t)g.ldb;
  const int r0 = tid >> 3;
  const int cswz = (tid & 7) ^ (r0 & 7);
  const bf16* gA = g.A + (size_t)(bm + r0) * lda + cswz * 8;
  const bf16* gB = g.B + (size_t)(bn + r0) * ldb + cswz * 8;
  bf16* lA = sA + tid * 8;
  bf16* lB = sB + tid * 8;

  for (int k0 = 0; k0 < D_DIM; k0 += 64) {
    __syncthreads();
#pragma unroll
    for (int j = 0; j < 4; ++j) {
      gl_lds16(gA + (size_t)(32 * j) * lda + k0, lA + j * 2048);
      gl_lds16(gB + (size_t)(32 * j) * ldb + k0, lB + j * 2048);
    }
    __syncthreads();
#pragma unroll
    for (int ks = 0; ks < 2; ++ks) {
      const int ch = ((ks * 4 + quad) ^ (l15 & 7)) * 8;
      bf16x8 af[4], bv[4];
#pragma unroll
      for (int t = 0; t < 4; ++t)
        af[t] = *(const bf16x8*)(sA + (wm + t * 16 + l15) * 64 + ch);
#pragma unroll
      for (int u = 0; u < 4; ++u)
        bv[u] = *(const bf16x8*)(sB + (wn + u * 16 + l15) * 64 + ch);
#pragma unroll
      for (int t = 0; t < 4; ++t)
#pragma unroll
        for (int u = 0; u < 4; ++u)
          acc[t][u] = __builtin_amdgcn_mfma_f32_16x16x32_bf16(af[t], bv[u], acc[t][u], 0, 0, 0);
    }
  }

  const int ldc = g.N;
#pragma unroll
  for (int t = 0; t < 4; ++t) {
    const int rbase = bm + wm + t * 16 + quad * 4;
    float rsum[4] = {0.f, 0.f, 0.f, 0.f};
#pragma unroll
    for (int u = 0; u < 4; ++u) {
      const int col = bn + wn + u * 16 + l15;
#pragma unroll
      for (int r = 0; r < 4; ++r) {
        float e = __expf(acc[t][u][r] * g.scale);
        g.outP8[(size_t)(rbase + r) * ldc + col] = to_fp8(e);
        rsum[r] += e;
      }
    }
#pragma unroll
    for (int m = 1; m < 16; m <<= 1)
#pragma unroll
      for (int r = 0; r < 4; ++r) rsum[r] += __shfl_xor(rsum[r], m, 64);
    if (l15 == 0)
#pragma unroll
      for (int r = 0; r < 4; ++r) atomicAdd(&g.lsum[rbase + r], rsum[r]);
  }
}

// ---------------------------------------------------------------- fp8 updates GEMM
// C[128x256] per block, 8 waves (512 thr), each wave 64x64. Single pass (INIT store).
// A: fp8 [4096, N] (P~), B: fp8 [768, N] (v^T). z-slice of K -> private bf16 partial.
struct F8Args {
  const unsigned char* A; const unsigned char* B;
  bf16* out;       // NZ partial buffers, each S_DIM*D_DIM, contiguous
  int lda, ldb;
};

__global__ __launch_bounds__(512) void k_upd(F8Args u) {
  __shared__ __align__(16) unsigned char sA[128 * 32];
  __shared__ __align__(16) unsigned char sB[256 * 32];
  const int tid  = threadIdx.x;
  const int wave = tid >> 6;
  const int lane = tid & 63;
  const int quad = lane >> 4;
  const int l15  = lane & 15;
  const int bm = blockIdx.y * 128;
  const int bn = blockIdx.x * 256;
  const int z  = blockIdx.z;
  const int wm = (wave >> 2) * 64;
  const int wn = (wave & 3) * 64;

  const unsigned char* A = u.A + (size_t)z * KSLICE;
  const unsigned char* B = u.B + (size_t)z * KSLICE;
  bf16* out = u.out + (size_t)z * S_DIM * D_DIM;

  f32x4 acc[4][4];
#pragma unroll
  for (int t = 0; t < 4; ++t)
#pragma unroll
    for (int u2 = 0; u2 < 4; ++u2) acc[t][u2] = (f32x4){0.f, 0.f, 0.f, 0.f};

  // staging per K-step: B = 512 segs of 16B (all threads), A = 256 segs (threads<256)
  const size_t lda = (size_t)u.lda, ldb = (size_t)u.ldb;
  const int rb = tid >> 1, hb = tid & 1;
  const unsigned char* gB = B + (size_t)(bn + rb) * ldb + ((hb ^ ((rb >> 2) & 1)) * 16);
  unsigned char* lB = sB + tid * 16;
  const int ta = tid & 255;
  const int ra = ta >> 1, ha = ta & 1;
  const unsigned char* gA = A + (size_t)(bm + ra) * lda + ((ha ^ ((ra >> 2) & 1)) * 16);
  unsigned char* lA = sA + ta * 16;
  const bool doA = (tid < 256);

  const int xh = (l15 >> 2) & 1;
  const int qoff = (((quad >> 1) ^ xh) * 16) + (quad & 1) * 8;

  for (int k0 = 0; k0 < KSLICE; k0 += 32) {
    __syncthreads();
    if (doA) gl_lds16(gA + k0, lA);
    gl_lds16(gB + k0, lB);
    __syncthreads();
    i64 af[4], bv[4];
#pragma unroll
    for (int t = 0; t < 4; ++t)
      af[t] = *(const i64*)(sA + (wm + t * 16 + l15) * 32 + qoff);
#pragma unroll
    for (int u2 = 0; u2 < 4; ++u2)
      bv[u2] = *(const i64*)(sB + (wn + u2 * 16 + l15) * 32 + qoff);
#pragma unroll
    for (int t = 0; t < 4; ++t)
#pragma unroll
      for (int u2 = 0; u2 < 4; ++u2)
        acc[t][u2] = __builtin_amdgcn_mfma_f32_16x16x32_fp8_fp8(af[t], bv[u2], acc[t][u2], 0, 0, 0);
  }

#pragma unroll
  for (int t = 0; t < 4; ++t) {
    const int rbase = bm + wm + t * 16 + quad * 4;
#pragma unroll
    for (int u2 = 0; u2 < 4; ++u2) {
      const int col = bn + wn + u2 * 16 + l15;
#pragma unroll
      for (int r = 0; r < 4; ++r)
        out[(size_t)(rbase + r) * D_DIM + col] = (bf16)acc[t][u2][r];
    }
  }
}

// ---------------------------------------------------------------- reduce NZ bf16 partials + /lsum
__global__ void reduce_div_k(const bf16* __restrict__ bufs, const float* __restrict__ lsum,
                             bf16* __restrict__ out) {
  const int idx = blockIdx.x * 256 + threadIdx.x;   // over S*192 bf16x4 groups
  const int row = idx / 192;
  const float inv = 1.0f / lsum[row];
  float s0 = 0.f, s1 = 0.f, s2 = 0.f, s3 = 0.f;
#pragma unroll
  for (int z = 0; z < NZ; ++z) {
    bf16x4 v = ((const bf16x4*)(bufs + (size_t)z * S_DIM * D_DIM))[idx];
    s0 += (float)v[0]; s1 += (float)v[1]; s2 += (float)v[2]; s3 += (float)v[3];
  }
  bf16x4 y;
  y[0] = (bf16)(s0 * inv); y[1] = (bf16)(s1 * inv);
  y[2] = (bf16)(s2 * inv); y[3] = (bf16)(s3 * inv);
  ((bf16x4*)out)[idx] = y;
}

// ---------------------------------------------------------------- LayerNorm row stats (wave/row)
__global__ void ln_stats_k(const float* __restrict__ X, float2* __restrict__ st) {
  const int row  = blockIdx.x * 4 + (threadIdx.x >> 6);
  const int lane = threadIdx.x & 63;
  const float4* xr = (const float4*)(X + (size_t)row * 768);
  float s = 0.f, ss = 0.f;
#pragma unroll
  for (int i = 0; i < 3; ++i) {
    float4 v = xr[lane + 64 * i];
    s  += v.x + v.y + v.z + v.w;
    ss += v.x * v.x + v.y * v.y + v.z * v.z + v.w * v.w;
  }
#pragma unroll
  for (int m = 1; m < 64; m <<= 1) { s += __shfl_xor(s, m, 64); ss += __shfl_xor(ss, m, 64); }
  if (lane == 0) {
    float mean = s * (1.f / 768.f);
    float var  = ss * (1.f / 768.f) - mean * mean;
    st[row] = make_float2(mean, rsqrtf(var + 1e-5f));
  }
}

// ---------------------------------------------------------------- LN apply -> bf16
__global__ void ln_apply_k(const float* __restrict__ X, const float2* __restrict__ st,
                           const float* __restrict__ gam, const float* __restrict__ bet,
                           bf16* __restrict__ Y) {
  const int idx = blockIdx.x * 256 + threadIdx.x;
  const int row = idx / 192, c4 = idx % 192;
  const float2 s = st[row];
  float4 x  = ((const float4*)(X + (size_t)row * 768))[c4];
  float4 g4 = ((const float4*)gam)[c4];
  float4 b4 = ((const float4*)bet)[c4];
  bf16x4 y;
  y[0] = (bf16)((x.x - s.x) * s.y * g4.x + b4.x);
  y[1] = (bf16)((x.y - s.x) * s.y * g4.y + b4.y);
  y[2] = (bf16)((x.z - s.x) * s.y * g4.z + b4.z);
  y[3] = (bf16)((x.w - s.x) * s.y * g4.w + b4.w);
  ((bf16x4*)(Y + (size_t)row * 768))[c4] = y;
}

// ---------------------------------------------------------------- f32 -> bf16
__global__ void cvt_k(const float* __restrict__ X, bf16* __restrict__ Y) {
  const int i = blockIdx.x * 256 + threadIdx.x;
  float4 v = ((const float4*)X)[i];
  bf16x4 y;
  y[0] = (bf16)v.x; y[1] = (bf16)v.y; y[2] = (bf16)v.z; y[3] = (bf16)v.w;
  ((bf16x4*)Y)[i] = y;
}

// ---------------------------------------------------------------- GRU gate (bf16 gx/gh)
__device__ inline float gru1(float xr, float xz, float xn, float hr, float hz, float hn, float sp) {
  float r = 1.f / (1.f + __expf(-(xr + hr)));
  float z = 1.f / (1.f + __expf(-(xz + hz)));
  float n = tanhf(xn + r * hn);
  return (1.f - z) * n + z * sp;
}

__global__ void gru_gate_k(const bf16* __restrict__ gx, const bf16* __restrict__ gh,
                           const float* __restrict__ slots, float* __restrict__ h) {
  const int idx = blockIdx.x * 256 + threadIdx.x;
  const int row = idx / 192, c4 = idx % 192;
  const bf16x4* gxr = (const bf16x4*)(gx + (size_t)row * 2304);
  const bf16x4* ghr = (const bf16x4*)(gh + (size_t)row * 2304);
  bf16x4 xr = gxr[c4], xz = gxr[192 + c4], xn = gxr[384 + c4];
  bf16x4 hr = ghr[c4], hz = ghr[192 + c4], hn = ghr[384 + c4];
  float4 sp = ((const float4*)(slots + (size_t)row * 768))[c4];
  float4 o;
  o.x = gru1((float)xr[0], (float)xz[0], (float)xn[0], (float)hr[0], (float)hz[0], (float)hn[0], sp.x);
  o.y = gru1((float)xr[1], (float)xz[1], (float)xn[1], (float)hr[1], (float)hz[1], (float)hn[1], sp.y);
  o.z = gru1((float)xr[2], (float)xz[2], (float)xn[2], (float)hr[2], (float)hz[2], (float)hn[2], sp.z);
  o.w = gru1((float)xr[3], (float)xz[3], (float)xn[3], (float)hr[3], (float)hz[3], (float)hn[3], sp.w);
  ((float4*)(h + (size_t)row * 768))[c4] = o;
}

// ---------------------------------------------------------------- host
extern "C" void kernel_launch(void* const* d_in, const int* in_sizes, int n_in,
                              void* d_out, int out_size, void* d_ws, size_t ws_size,
                              hipStream_t stream) {
  (void)in_sizes; (void)n_in; (void)out_size; (void)ws_size;
  const float* cand  = (const float*)d_in[0];
  const float* pano  = (const float*)d_in[1];
  const float* Wq  = (const float*)d_in[2];  const float* bq  = (const float*)d_in[3];
  const float* Wk  = (const float*)d_in[4];  const float* bk  = (const float*)d_in[5];
  const float* Wv  = (const float*)d_in[6];  const float* bv  = (const float*)d_in[7];
  const float* Wih = (const float*)d_in[8];  const float* bih = (const float*)d_in[9];
  const float* Whh = (const float*)d_in[10]; const float* bhh = (const float*)d_in[11];
  const float* W1  = (const float*)d_in[12]; const float* b1  = (const float*)d_in[13];
  const float* W2  = (const float*)d_in[14]; const float* b2  = (const float*)d_in[15];
  const float* g_in = (const float*)d_in[16]; const float* be_in = (const float*)d_in[17];
  const float* g_sl = (const float*)d_in[18]; const float* be_sl = (const float*)d_in[19];
  const float* g_ff = (const float*)d_in[20]; const float* be_ff = (const float*)d_in[21];

  const size_t WU = (size_t)D_DIM * D_DIM;

  char* base = (char*)d_ws;
  size_t off = 0;
  auto alloc = [&](size_t bytes) -> void* {
    void* r = base + off;
    off = (off + bytes + 255) & ~(size_t)255;
    return r;
  };

  bf16* wq_bf  = (bf16*)alloc(WU * 2);
  bf16* wk_bf  = (bf16*)alloc(WU * 2);
  bf16* wv_bf  = (bf16*)alloc(WU * 2);
  bf16* wih_bf = (bf16*)alloc(3 * WU * 2);
  bf16* whh_bf = (bf16*)alloc(3 * WU * 2);
  bf16* w1_bf  = (bf16*)alloc(WU * 2);
  bf16* w2_bf  = (bf16*)alloc(WU * 2);
  bf16* k_bf   = (bf16*)alloc((size_t)N_DIM * D_DIM * 2);
  unsigned char* vt_f8 = (unsigned char*)alloc((size_t)N_DIM * D_DIM);  // [768,16384] fp8
  float* slots = (float*)alloc((size_t)S_DIM * D_DIM * 4);
  bf16* slots_bf = (bf16*)alloc((size_t)S_DIM * D_DIM * 2);
  float2* statsP = (float2*)alloc((size_t)N_DIM * 8);
  float2* statsS = (float2*)alloc((size_t)S_DIM * 8);
  bf16* slotsln = (bf16*)alloc((size_t)S_DIM * D_DIM * 2);   // also hln (disjoint lifetime)
  bf16* q_bf    = (bf16*)alloc((size_t)S_DIM * D_DIM * 2);   // also m1 (disjoint lifetime)
  bf16* upd_bf  = (bf16*)alloc((size_t)S_DIM * D_DIM * 2);
  float* lsum   = (float*)alloc((size_t)S_DIM * 4);
  bf16* hln_bf = slotsln;
  bf16* m1_bf  = q_bf;
  // arena 112 MiB:
  //  attn phase: [0,64) P~ fp8 (S x N) | [64,112) partials (NZ=8 x 6 MiB bf16)
  //  gru  phase: [0,18) gx | [18,36) gh | [36,48) hbuf (f32)
  //  setup     : [0,24) panoln
  const size_t PCH = (size_t)S_DIM * N_DIM;             // 64 MiB fp8
  const size_t PBF = (size_t)NZ * S_DIM * D_DIM * 2;    // 48 MiB
  char* arena = (char*)alloc(PCH + PBF);
  bf16* panoln = (bf16*)arena;
  unsigned char* Pfull = (unsigned char*)arena;
  bf16* pbufs = (bf16*)(arena + PCH);
  bf16* gx = (bf16*)arena;
  bf16* gh = (bf16*)(arena + (size_t)S_DIM * 3 * D_DIM * 2);
  float* hbuf = (float*)(arena + 2 * (size_t)S_DIM * 3 * D_DIM * 2);

  // ---- weights to bf16
  cvt_k<<<dim3(WU / 1024), 256, 0, stream>>>(Wq, wq_bf);
  cvt_k<<<dim3(WU / 1024), 256, 0, stream>>>(Wk, wk_bf);
  cvt_k<<<dim3(WU / 1024), 256, 0, stream>>>(Wv, wv_bf);
  cvt_k<<<dim3(3 * WU / 1024), 256, 0, stream>>>(Wih, wih_bf);
  cvt_k<<<dim3(3 * WU / 1024), 256, 0, stream>>>(Whh, whh_bf);
  cvt_k<<<dim3(WU / 1024), 256, 0, stream>>>(W1, w1_bf);
  cvt_k<<<dim3(WU / 1024), 256, 0, stream>>>(W2, w2_bf);

  // ---- pano LN, k (bf16), v^T (fp8)
  ln_stats_k<<<dim3(N_DIM / 4), 256, 0, stream>>>(pano, statsP);
  ln_apply_k<<<dim3(N_DIM * 192 / 256), 256, 0, stream>>>(pano, statsP, g_in, be_in, panoln);
  {
    GemmArgs ak{};
    ak.A = panoln; ak.B = wk_bf; ak.bias = bk; ak.outB = k_bf;
    ak.M = N_DIM; ak.N = D_DIM; ak.K = D_DIM; ak.lda = D_DIM; ak.ldb = D_DIM;
    k_kgemm<<<dim3(6, 128), 256, 0, stream>>>(ak);
    GemmArgs av{};  // v^T = Wv @ panoln^T -> fp8 [768, 16384]
    av.A = wv_bf; av.B = panoln; av.bias = bv; av.outP8 = vt_f8;
    av.M = D_DIM; av.N = N_DIM; av.K = D_DIM; av.lda = D_DIM; av.ldb = D_DIM;
    k_vtgemm<<<dim3(128, 6), 256, 0, stream>>>(av);
  }

  // ---- slots init
  hipMemcpyAsync(slots, cand, (size_t)S_DIM * D_DIM * 4, hipMemcpyDeviceToDevice, stream);
  cvt_k<<<dim3(S_DIM * D_DIM / 1024), 256, 0, stream>>>(cand, slots_bf);

  for (int iter = 0; iter < 3; ++iter) {
    // q = LN(slots) @ Wq^T + bq
    ln_stats_k<<<dim3(S_DIM / 4), 256, 0, stream>>>(slots, statsS);
    ln_apply_k<<<dim3(S_DIM * 192 / 256), 256, 0, stream>>>(slots, statsS, g_sl, be_sl, slotsln);
    GemmArgs aq{};
    aq.A = slotsln; aq.B = wq_bf; aq.bias = bq; aq.outB = q_bf;
    aq.M = S_DIM; aq.N = D_DIM; aq.K = D_DIM; aq.lda = D_DIM; aq.ldb = D_DIM;
    k_qgemm<<<dim3(6, 32), 256, 0, stream>>>(aq);

    // attention, single pass over full N
    hipMemsetAsync(lsum, 0, (size_t)S_DIM * 4, stream);
    {
      GemmArgs ad{};
      ad.A = q_bf; ad.B = k_bf;
      ad.outP8 = Pfull; ad.lsum = lsum; ad.scale = SCALE;
      ad.M = S_DIM; ad.N = N_DIM; ad.K = D_DIM; ad.lda = D_DIM; ad.ldb = D_DIM;
      k_dots<<<dim3(N_DIM / 128, S_DIM / 128), 256, 0, stream>>>(ad);

      F8Args au{};
      au.A = Pfull; au.B = vt_f8;
      au.out = pbufs; au.lda = N_DIM; au.ldb = N_DIM;
      k_upd<<<dim3(3, 32, NZ), 512, 0, stream>>>(au);
    }
    reduce_div_k<<<dim3(S_DIM * 192 / 256), 256, 0, stream>>>(pbufs, lsum, upd_bf);

    // GRU: gx = upd @ Wih^T + bih ; gh = slots @ Whh^T + bhh
    {
      GemmArgs agx{};
      agx.A = upd_bf; agx.B = wih_bf; agx.bias = bih; agx.outB = gx;
      agx.M = S_DIM; agx.N = 3 * D_DIM; agx.K = D_DIM; agx.lda = D_DIM; agx.ldb = D_DIM;
      GemmArgs agh{};
      agh.A = slots_bf; agh.B = whh_bf; agh.bias = bhh; agh.outB = gh;
      agh.M = S_DIM; agh.N = 3 * D_DIM; agh.K = D_DIM; agh.lda = D_DIM; agh.ldb = D_DIM;
      k_dual<<<dim3(36, 32), 256, 0, stream>>>(agx, agh, 18);
    }
    gru_gate_k<<<dim3(S_DIM * 192 / 256), 256, 0, stream>>>(gx, gh, slots, hbuf);

    // MLP with residual
    ln_stats_k<<<dim3(S_DIM / 4), 256, 0, stream>>>(hbuf, statsS);
    ln_apply_k<<<dim3(S_DIM * 192 / 256), 256, 0, stream>>>(hbuf, statsS, g_ff, be_ff, hln_bf);
    GemmArgs am1{};
    am1.A = hln_bf; am1.B = w1_bf; am1.bias = b1; am1.outB = m1_bf;
    am1.M = S_DIM; am1.N = D_DIM; am1.K = D_DIM; am1.lda = D_DIM; am1.ldb = D_DIM;
    k_relu<<<dim3(6, 32), 256, 0, stream>>>(am1);
    GemmArgs am2{};
    am2.A = m1_bf; am2.B = w2_bf; am2.bias = b2; am2.res = hbuf;
    am2.outF = (iter == 2) ? (float*)d_out : slots;
    am2.M = S_DIM; am2.N = D_DIM; am2.K = D_DIM; am2.lda = D_DIM; am2.ldb = D_DIM;
    k_resid<<<dim3(6, 32), 256, 0, stream>>>(am2);

    if (iter < 2)
      cvt_k<<<dim3(S_DIM * D_DIM / 1024), 256, 0, stream>>>(slots, slots_bf);
  }
}